// Round 2
// baseline (985.221 us; speedup 1.0000x reference)
//
#include <hip/hip_runtime.h>
#include <math.h>

#define WAVES_PER_BLOCK 4
#define BLOCK_SIZE (WAVES_PER_BLOCK * 64)
#define GRID_BLOCKS 1024

// Fused: [GraphAttn(125,64) x2 -> BN+ReLU] -> [GraphAttn(64,32) cross x2 -> BN+ReLU]
//        -> concat(320) -> Linear(320,13)
// One wave per batch element b. lane = output-feature column.
// Stage1: lane l holds hA[i][l], hN[i][l] (i=0..4). Stage2: lanes 0..31 = gA cols,
// lanes 32..63 = gN cols. Softmax is over dim=1 (normalize over i for each j),
// contraction over j — replicating the reference exactly.

__device__ __forceinline__ void attn_bn(const float* s, const float* t, const float* h,
                                        const float* bns, const float* bnt, float* o) {
  float acc[5] = {0.f, 0.f, 0.f, 0.f, 0.f};
#pragma unroll
  for (int j = 0; j < 5; ++j) {
    float col[5];
    float mx = -1e30f;
#pragma unroll
    for (int i = 0; i < 5; ++i) {
      float e = s[i] + t[j];
      e = (e > 0.f) ? e : 0.2f * e;  // LeakyReLU(0.2)
      col[i] = e;
      mx = fmaxf(mx, e);
    }
    float sum = 0.f;
#pragma unroll
    for (int i = 0; i < 5; ++i) {
      col[i] = __expf(col[i] - mx);
      sum += col[i];
    }
    float hj = h[j] / sum;  // attn[i][j] * h[j] = col[i]/sum * h[j]
#pragma unroll
    for (int i = 0; i < 5; ++i) acc[i] += col[i] * hj;
  }
  // eval BatchNorm (folded scale/shift) + ReLU, channel = i
#pragma unroll
  for (int i = 0; i < 5; ++i) o[i] = fmaxf(acc[i] * bns[i] + bnt[i], 0.f);
}

__global__ __launch_bounds__(BLOCK_SIZE, 2) void gat_fused(
    const float* __restrict__ x,
    const float* __restrict__ Wt1, const float* __restrict__ a11, const float* __restrict__ a21,
    const float* __restrict__ g1, const float* __restrict__ b1,
    const float* __restrict__ m1, const float* __restrict__ v1,
    const float* __restrict__ Wt2, const float* __restrict__ a12, const float* __restrict__ a22,
    const float* __restrict__ g2, const float* __restrict__ b2,
    const float* __restrict__ m2, const float* __restrict__ v2,
    const float* __restrict__ Wl, const float* __restrict__ bl,
    float* __restrict__ out, int B) {
  // LDS: ~71 KB/block -> 2 blocks/CU
  __shared__ float s_wt1t[128 * 64];  // [k][f], k padded to 128 with zeros
  __shared__ float s_wt2t[64 * 32];   // [k][f]
  __shared__ float s_a11[64], s_a21[64], s_a12[32], s_a22[32];
  __shared__ float s_bn1s[5], s_bn1t[5], s_bn2s[5], s_bn2t[5];
  __shared__ float s_bl[16];
  __shared__ float s_x[WAVES_PER_BLOCK][5 * 256];   // per row i: [0..124]=xa,[125..127]=0,[128..252]=xn,[253..255]=0
  __shared__ float s_xp[WAVES_PER_BLOCK][5 * 128];  // per row i: [0..63]=xa1, [64..127]=xn1

  const int tid = threadIdx.x;
  const int lane = tid & 63;
  const int wv = tid >> 6;

  // ---- one-time block preload ----
  for (int idx = tid; idx < 64 * 125; idx += BLOCK_SIZE) {
    int f = idx / 125, k = idx - f * 125;
    s_wt1t[k * 64 + f] = Wt1[idx];
  }
  for (int idx = tid; idx < 3 * 64; idx += BLOCK_SIZE) {
    s_wt1t[(125 + (idx >> 6)) * 64 + (idx & 63)] = 0.f;  // zero K-pad rows
  }
  for (int idx = tid; idx < 32 * 64; idx += BLOCK_SIZE) {
    int f = idx >> 6, k = idx & 63;
    s_wt2t[k * 32 + f] = Wt2[idx];
  }
  if (tid < 64) { s_a11[tid] = a11[tid]; s_a21[tid] = a21[tid]; }
  if (tid < 32) { s_a12[tid] = a12[tid]; s_a22[tid] = a22[tid]; }
  if (tid < 5) {
    float inv1 = rsqrtf(v1[tid] + 1e-5f);
    float sc1 = g1[tid] * inv1;
    s_bn1s[tid] = sc1;
    s_bn1t[tid] = b1[tid] - m1[tid] * sc1;
    float inv2 = rsqrtf(v2[tid] + 1e-5f);
    float sc2 = g2[tid] * inv2;
    s_bn2s[tid] = sc2;
    s_bn2t[tid] = b2[tid] - m2[tid] * sc2;
  }
  if (tid < 13) s_bl[tid] = bl[tid];
  __syncthreads();

  // zero this wave's x-pad columns once (wave-private buffer, no barrier needed)
  if (lane < 30) {
    int i = lane / 6, r = lane - (lane / 6) * 6;
    int col = (r < 3) ? (125 + r) : (250 + r);  // 125,126,127 / 253,254,255
    s_x[wv][i * 256 + col] = 0.f;
  }

  const float va11 = s_a11[lane], va21 = s_a21[lane];
  const int f2 = lane & 31;
  const int half = lane >> 5;
  const float va12 = s_a12[f2], va22 = s_a22[f2];

  const int gw = blockIdx.x * WAVES_PER_BLOCK + wv;
  const int nw = GRID_BLOCKS * WAVES_PER_BLOCK;

  for (int b = gw; b < B; b += nw) {
    // ---- stage x[b] (1250 floats) into LDS ----
    const float* xb = x + (size_t)b * 1250;
#pragma unroll
    for (int t = 0; t < 20; ++t) {
      int j = lane + t * 64;
      if (j < 1250) {
        int i = j / 250, c = j - i * 250;
        int dst = i * 256 + (c < 125 ? c : c + 3);
        s_x[wv][dst] = xb[j];
      }
    }

    // ---- stage-1 GEMM: hA[i][lane], hN[i][lane] ----
    float hA[5] = {0, 0, 0, 0, 0}, hN[5] = {0, 0, 0, 0, 0};
    const float* sx = &s_x[wv][0];
#pragma unroll 4
    for (int k4 = 0; k4 < 128; k4 += 4) {
      float w0 = s_wt1t[(k4 + 0) * 64 + lane];
      float w1 = s_wt1t[(k4 + 1) * 64 + lane];
      float w2 = s_wt1t[(k4 + 2) * 64 + lane];
      float w3 = s_wt1t[(k4 + 3) * 64 + lane];
#pragma unroll
      for (int i = 0; i < 5; ++i) {
        float4 xa4 = *reinterpret_cast<const float4*>(&sx[i * 256 + k4]);
        float4 xn4 = *reinterpret_cast<const float4*>(&sx[i * 256 + 128 + k4]);
        hA[i] += xa4.x * w0 + xa4.y * w1 + xa4.z * w2 + xa4.w * w3;
        hN[i] += xn4.x * w0 + xn4.y * w1 + xn4.z * w2 + xn4.w * w3;
      }
    }

    // ---- stage-1 scores: 20 wave-wide dots via butterfly ----
    float sA[5], tA[5], sN[5], tN[5];
#pragma unroll
    for (int i = 0; i < 5; ++i) {
      sA[i] = hA[i] * va11;
      tA[i] = hA[i] * va21;
      sN[i] = hN[i] * va11;
      tN[i] = hN[i] * va21;
    }
#pragma unroll
    for (int st = 0; st < 6; ++st) {
      int off = 32 >> st;
#pragma unroll
      for (int i = 0; i < 5; ++i) {
        sA[i] += __shfl_xor(sA[i], off);
        tA[i] += __shfl_xor(tA[i], off);
        sN[i] += __shfl_xor(sN[i], off);
        tN[i] += __shfl_xor(tN[i], off);
      }
    }

    // ---- attention + BN1 + ReLU ----
    float xa1[5], xn1[5];
    attn_bn(sA, tA, hA, s_bn1s, s_bn1t, xa1);
    attn_bn(sN, tN, hN, s_bn1s, s_bn1t, xn1);

    // publish to LDS for stage-2 (wave-private, in-order LDS)
#pragma unroll
    for (int i = 0; i < 5; ++i) {
      s_xp[wv][i * 128 + lane] = xa1[i];
      s_xp[wv][i * 128 + 64 + lane] = xn1[i];
    }

    // ---- stage-2 GEMM: lanes 0..31 -> gA, 32..63 -> gN ----
    float g[5] = {0, 0, 0, 0, 0};
    const float* sxp = &s_xp[wv][half * 64];
#pragma unroll 4
    for (int k4 = 0; k4 < 64; k4 += 4) {
      float w0 = s_wt2t[(k4 + 0) * 32 + f2];
      float w1 = s_wt2t[(k4 + 1) * 32 + f2];
      float w2 = s_wt2t[(k4 + 2) * 32 + f2];
      float w3 = s_wt2t[(k4 + 3) * 32 + f2];
#pragma unroll
      for (int i = 0; i < 5; ++i) {
        float4 p4 = *reinterpret_cast<const float4*>(&sxp[i * 128 + k4]);
        g[i] += p4.x * w0 + p4.y * w1 + p4.z * w2 + p4.w * w3;
      }
    }

    // ---- stage-2 scores: half-wave reduce, then cross-half exchange ----
    float u[5], v[5];
#pragma unroll
    for (int i = 0; i < 5; ++i) {
      u[i] = g[i] * va12;
      v[i] = g[i] * va22;
    }
#pragma unroll
    for (int st = 0; st < 5; ++st) {
      int off = 16 >> st;
#pragma unroll
      for (int i = 0; i < 5; ++i) {
        u[i] += __shfl_xor(u[i], off);
        v[i] += __shfl_xor(v[i], off);
      }
    }
#pragma unroll
    for (int i = 0; i < 5; ++i) v[i] = __shfl_xor(v[i], 32);  // get other half's g.a22

    // ---- attention2 + BN2 + ReLU: z[i] = (half==0 ? ya2 : yn2)[i][f2] ----
    float z[5];
    attn_bn(u, v, g, s_bn2s, s_bn2t, z);

    // ---- final Linear(320,13): feat[c], c = i*64 + lane ----
    float r[13];
#pragma unroll
    for (int o = 0; o < 13; ++o) r[o] = (lane == 0) ? s_bl[o] : 0.f;
    const float* wl = Wl + lane;
#pragma unroll
    for (int i = 0; i < 5; ++i) {
      float zi = z[i];
#pragma unroll
      for (int o = 0; o < 13; ++o) r[o] += zi * wl[o * 320 + i * 64];
    }
#pragma unroll
    for (int st = 0; st < 6; ++st) {
      int off = 32 >> st;
#pragma unroll
      for (int o = 0; o < 13; ++o) r[o] += __shfl_xor(r[o], off);
    }
    float ov = r[0];
#pragma unroll
    for (int o = 1; o < 13; ++o) ov = (lane == o) ? r[o] : ov;
    if (lane < 13) out[(size_t)b * 13 + lane] = ov;
  }
}

extern "C" void kernel_launch(void* const* d_in, const int* in_sizes, int n_in,
                              void* d_out, int out_size, void* d_ws, size_t ws_size,
                              hipStream_t stream) {
  (void)n_in; (void)out_size; (void)d_ws; (void)ws_size;
  const float* x   = (const float*)d_in[0];
  const float* Wt1 = (const float*)d_in[1];
  const float* a11 = (const float*)d_in[2];
  const float* a21 = (const float*)d_in[3];
  const float* g1  = (const float*)d_in[4];
  const float* b1  = (const float*)d_in[5];
  const float* m1  = (const float*)d_in[6];
  const float* v1  = (const float*)d_in[7];
  const float* Wt2 = (const float*)d_in[8];
  const float* a12 = (const float*)d_in[9];
  const float* a22 = (const float*)d_in[10];
  const float* g2  = (const float*)d_in[11];
  const float* b2  = (const float*)d_in[12];
  const float* m2  = (const float*)d_in[13];
  const float* v2  = (const float*)d_in[14];
  const float* Wl  = (const float*)d_in[15];
  const float* bl  = (const float*)d_in[16];
  float* out = (float*)d_out;

  int B = in_sizes[0] / 1250;

  hipLaunchKernelGGL(gat_fused, dim3(GRID_BLOCKS), dim3(BLOCK_SIZE), 0, stream,
                     x, Wt1, a11, a21, g1, b1, m1, v1,
                     Wt2, a12, a22, g2, b2, m2, v2, Wl, bl, out, B);
}